// Round 4
// baseline (526.568 us; speedup 1.0000x reference)
//
#include <hip/hip_runtime.h>

// OT Sinkhorn, B=32, N=512, OUT=56 (pad 64), 100 iters — MFMA, 16-wave phases.
// Phase A (split-K=4): S[i][j] = sum_n (Ky[i,n]*u[n])*Kx[j,n]
//   wave w: group g=w>>2 (K-slice g*128), quadrant q=w&3 (2x2 16-tiles).
//   A = KyT(LDS)*u(bcast), B = Kx register cache. Partials -> LDS, reduced in v-step.
// Phase B: T'[j][n] = sum_i V[i,j]*Ky[n,i]; A=VT(LDS), B=Ky regs, K=64.
// r[n] = sum_j Kx[n,j]*T'[j][n] via reg-cached Kx slice + 2 shuffles.

#define NPTS 512
#define GRID 3136
#define OUTD 56

typedef _Float16 h8  __attribute__((ext_vector_type(8)));
typedef _Float16 h4v __attribute__((ext_vector_type(4)));
typedef float    f4  __attribute__((ext_vector_type(4)));

#define OFF_RED 0          // double[16]                 128 B
#define OFF_Y   128        // float[512]                2048 B
#define OFF_X   2176       // float[512]                2048 B
#define OFF_UH  4224       // f16[512]                  1024 B
#define OFF_VT  5248       // f16 [64][72]              9216 B
#define OFF_KYT 14464      // f16 [64][512] swizzled   65536 B
#define OFF_SP  80000      // f32 [16][4][256]         65536 B
#define LDS_TOTAL 145536

__device__ __forceinline__ float coordf(int k) {
    // ((8k+4)/448)*2 - 1
    return (float)(8 * k + 4) * (1.0f / 224.0f) - 1.0f;
}

// swizzled offset (halfs) into a [64][512] f16 table; c8 = 8-half chunk idx 0..63
__device__ __forceinline__ int tr_off(int row, int c8) {
    return row * 512 + ((c8 ^ (row & 7)) << 3);
}

__device__ double blockReduce(double x, double* sRed, int tid) {
    #pragma unroll
    for (int o = 32; o > 0; o >>= 1) x += __shfl_down(x, o);
    int wid = tid >> 6;
    if ((tid & 63) == 0) sRed[wid] = x;
    __syncthreads();
    if (tid < 16) {
        x = sRed[tid];
        #pragma unroll
        for (int o = 8; o > 0; o >>= 1) x += __shfl_down(x, o);
    }
    __syncthreads();
    return x;  // valid on tid 0
}

extern "C" __global__ __launch_bounds__(1024)
void ot_sinkhorn_mfma(const float* __restrict__ pred,
                      const float* __restrict__ normed,
                      const float* __restrict__ tpts,
                      double* __restrict__ ws)
{
    extern __shared__ char smem[];
    double*    sRed = (double*)(smem + OFF_RED);
    float*     sY   = (float*)(smem + OFF_Y);
    float*     sX   = (float*)(smem + OFF_X);
    _Float16*  sUh  = (_Float16*)(smem + OFF_UH);
    _Float16*  sVT  = (_Float16*)(smem + OFF_VT);
    _Float16*  sKyT = (_Float16*)(smem + OFF_KYT);
    float*     sSp  = (float*)(smem + OFF_SP);

    const int tid  = threadIdx.x;
    const int w    = tid >> 6;
    const int lane = tid & 63;
    const int quad = lane >> 4;
    const int l16  = lane & 15;
    const int s    = blockIdx.x;
    const float* tp = tpts  + (size_t)s * NPTS * 2;
    const float* bv = normed + (size_t)s * GRID;
    const float* sd = pred   + (size_t)s * GRID;

    // ---------------- setup ----------------
    if (tid < NPTS) {
        sX[tid]  = tp[2 * tid + 0] * (2.0f / 448.0f) - 1.0f;
        sY[tid]  = tp[2 * tid + 1] * (2.0f / 448.0f) - 1.0f;
        sUh[tid] = (_Float16)(1.0f / 512.0f);
    }
    __syncthreads();

    // static KyT[i][n] table (rows >=56 zeroed)
    {
        int n = tid >> 1, i0 = (tid & 1) * 32;
        float y = sY[n];
        #pragma unroll
        for (int ii = 0; ii < 32; ++ii) {
            int i = i0 + ii;
            float d = y - coordf(i);
            _Float16 ky = (i < OUTD) ? (_Float16)__expf(-d * d * 0.1f) : (_Float16)0.0f;
            sKyT[tr_off(i, n >> 3) + (n & 7)] = ky;
        }
    }

    const int g   = w >> 2;         // phase-A K-group (slice g*128)
    const int q   = w & 3;          // phase-A tile quadrant
    const int it0 = (q & 2);        // i-tile base (0 or 2)
    const int jt0 = (q & 1) * 2;    // j-tile base
    const int nt0 = w * 2;          // phase-B n-tile pair

    // register caches (static)
    // kxB[b][ks]: phase-A B-frag Kx[j][n], j=(jt0+b)*16+l16, n=g*128+ks*32+quad*8+e
    h8 kxB[2][4];
    #pragma unroll
    for (int b = 0; b < 2; ++b) {
        int j = (jt0 + b) * 16 + l16;
        float cj = coordf(j);
        #pragma unroll
        for (int ks = 0; ks < 4; ++ks)
            #pragma unroll
            for (int e = 0; e < 8; ++e) {
                int n = g * 128 + ks * 32 + quad * 8 + e;
                float d = sX[n] - cj;
                kxB[b][ks][e] = (j < OUTD) ? (_Float16)__expf(-d * d * 0.1f)
                                           : (_Float16)0.0f;
            }
    }
    // kyA[ntl][ks]: phase-B B-frag Ky[n][i], n=(nt0+ntl)*16+l16, i=ks*32+quad*8+e
    h8 kyA[2][2];
    #pragma unroll
    for (int ntl = 0; ntl < 2; ++ntl) {
        int n = (nt0 + ntl) * 16 + l16;
        float y = sY[n];
        #pragma unroll
        for (int ks = 0; ks < 2; ++ks)
            #pragma unroll
            for (int e = 0; e < 8; ++e) {
                int i = ks * 32 + quad * 8 + e;
                float d = y - coordf(i);
                kyA[ntl][ks][e] = (i < OUTD) ? (_Float16)__expf(-d * d * 0.1f)
                                             : (_Float16)0.0f;
            }
    }
    // kxR[ntl][h]: r-step Kx[n][j], j=jt*16+quad*4+r, element (jt&1)*4+r, h=jt>>1
    h8 kxR[2][2];
    #pragma unroll
    for (int ntl = 0; ntl < 2; ++ntl) {
        int n = (nt0 + ntl) * 16 + l16;
        float x = sX[n];
        #pragma unroll
        for (int jt = 0; jt < 4; ++jt)
            #pragma unroll
            for (int r = 0; r < 4; ++r) {
                int j = jt * 16 + quad * 4 + r;
                float d = x - coordf(j);
                kxR[ntl][jt >> 1][(jt & 1) * 4 + r] =
                    (j < OUTD) ? (_Float16)__expf(-d * d * 0.1f) : (_Float16)0.0f;
            }
    }
    __syncthreads();

    const f4 fz = {0.f, 0.f, 0.f, 0.f};
    // v-step tile assignment: wave w -> tile (it=w>>2, jt=w&3)
    const int vit = w >> 2, vjt = w & 3;
    const int vq  = (vit & 2) | (vjt >> 1);
    const int vt  = ((vit & 1) << 1) | (vjt & 1);
    const int vj  = vjt * 16 + l16;
    const int vib = vit * 16 + quad * 4;

    // ---------------- 100 Sinkhorn iterations ----------------
    for (int iter = 0; iter < 100; ++iter) {
        // ---- phase A: partial S over K-slice g*128..+128, 2x2 tiles
        f4 accA[2][2];
        accA[0][0] = fz; accA[0][1] = fz; accA[1][0] = fz; accA[1][1] = fz;
        #pragma unroll
        for (int ks = 0; ks < 4; ++ks) {
            int kg = g * 128 + ks * 32;
            int c8 = (kg >> 3) + quad;
            h8 uf = *(const h8*)(sUh + kg + quad * 8);   // 16-lane broadcast
            h8 a0 = *(const h8*)(sKyT + tr_off((it0 + 0) * 16 + l16, c8));
            h8 a1 = *(const h8*)(sKyT + tr_off((it0 + 1) * 16 + l16, c8));
            a0 *= uf; a1 *= uf;
            accA[0][0] = __builtin_amdgcn_mfma_f32_16x16x32_f16(a0, kxB[0][ks], accA[0][0], 0, 0, 0);
            accA[0][1] = __builtin_amdgcn_mfma_f32_16x16x32_f16(a0, kxB[1][ks], accA[0][1], 0, 0, 0);
            accA[1][0] = __builtin_amdgcn_mfma_f32_16x16x32_f16(a1, kxB[0][ks], accA[1][0], 0, 0, 0);
            accA[1][1] = __builtin_amdgcn_mfma_f32_16x16x32_f16(a1, kxB[1][ks], accA[1][1], 0, 0, 0);
        }
        // write partials: slot (w*4 + a*2+b), lane-contiguous f4
        #pragma unroll
        for (int a = 0; a < 2; ++a)
            #pragma unroll
            for (int b = 0; b < 2; ++b)
                *(f4*)(sSp + ((w * 4 + a * 2 + b) << 8) + lane * 4) = accA[a][b];
        __syncthreads();

        // ---- v-step: each wave reduces one 16x16 tile, v = b/(S+eps), write VT
        {
            f4 S = fz;
            #pragma unroll
            for (int g2 = 0; g2 < 4; ++g2)
                S += *(const f4*)(sSp + (((g2 * 4 + vq) * 4 + vt) << 8) + lane * 4);
            h4v vv;
            #pragma unroll
            for (int r = 0; r < 4; ++r) {
                int i = vib + r;
                float v = 0.f;
                if (i < OUTD && vj < OUTD)
                    v = bv[i * OUTD + vj] / (S[r] + 1e-16f);
                vv[r] = (_Float16)v;
            }
            *(h4v*)(sVT + vj * 72 + vib) = vv;
        }
        __syncthreads();

        // ---- phase B: T'[j][n] for 2 n-tiles; af shared across ntl
        h8 af[2][4];
        #pragma unroll
        for (int ks = 0; ks < 2; ++ks)
            #pragma unroll
            for (int jt = 0; jt < 4; ++jt)
                af[ks][jt] = *(const h8*)(sVT + (jt * 16 + l16) * 72 + ks * 32 + quad * 8);
        #pragma unroll
        for (int ntl = 0; ntl < 2; ++ntl) {
            f4 acc[4] = {fz, fz, fz, fz};
            #pragma unroll
            for (int ks = 0; ks < 2; ++ks)
                #pragma unroll
                for (int jt = 0; jt < 4; ++jt)
                    acc[jt] = __builtin_amdgcn_mfma_f32_16x16x32_f16(
                        af[ks][jt], kyA[ntl][ks], acc[jt], 0, 0, 0);
            // r-step
            float rs = 0.f;
            #pragma unroll
            for (int jt = 0; jt < 4; ++jt)
                #pragma unroll
                for (int r = 0; r < 4; ++r)
                    rs += (float)kxR[ntl][jt >> 1][(jt & 1) * 4 + r] * acc[jt][r];
            rs += __shfl_xor(rs, 16);
            rs += __shfl_xor(rs, 32);
            if (quad == 0) {
                int n = (nt0 + ntl) * 16 + l16;
                sUh[n] = (_Float16)((1.0f / 512.0f) / (rs + 1e-16f));
            }
        }
        __syncthreads();
    }

    // ---------------- epilogue ----------------
    // E1: ot, t1, sc from beta = 10*ln(v+1e-16)
    double ot = 0.0, t1d = 0.0, sc = 0.0;
    for (int m = tid; m < GRID; m += 1024) {
        int i = m / OUTD, j = m - i * OUTD;
        float v = (float)sVT[j * 72 + i];
        float beta = 10.0f * logf(v + 1e-16f);
        float sdm = sd[m];
        ot  += (double)(bv[m] * beta);
        t1d += (double)(sdm * beta);
        sc  += (double)sdm;
    }
    ot  = blockReduce(ot, sRed, tid);
    t1d = blockReduce(t1d, sRed, tid);
    sc  = blockReduce(sc, sRed, tid);

    // E2: wd = sum_n u_n sum_j [ Kx*(dy^2 T') + Kx*dx^2*T' ] via kyA/kyQ MFMAs
    double wdd = 0.0;
    {
        h8 kyQ[2][2];
        #pragma unroll
        for (int ntl = 0; ntl < 2; ++ntl) {
            int n = (nt0 + ntl) * 16 + l16;
            float y = sY[n];
            #pragma unroll
            for (int ks = 0; ks < 2; ++ks)
                #pragma unroll
                for (int e = 0; e < 8; ++e) {
                    int i = ks * 32 + quad * 8 + e;
                    float d = y - coordf(i);
                    kyQ[ntl][ks][e] = (_Float16)((float)kyA[ntl][ks][e] * d * d);
                }
        }
        h8 af[2][4];
        #pragma unroll
        for (int ks = 0; ks < 2; ++ks)
            #pragma unroll
            for (int jt = 0; jt < 4; ++jt)
                af[ks][jt] = *(const h8*)(sVT + (jt * 16 + l16) * 72 + ks * 32 + quad * 8);
        #pragma unroll
        for (int ntl = 0; ntl < 2; ++ntl) {
            f4 tA[4] = {fz, fz, fz, fz}, tQ[4] = {fz, fz, fz, fz};
            #pragma unroll
            for (int ks = 0; ks < 2; ++ks)
                #pragma unroll
                for (int jt = 0; jt < 4; ++jt) {
                    tA[jt] = __builtin_amdgcn_mfma_f32_16x16x32_f16(af[ks][jt], kyA[ntl][ks], tA[jt], 0, 0, 0);
                    tQ[jt] = __builtin_amdgcn_mfma_f32_16x16x32_f16(af[ks][jt], kyQ[ntl][ks], tQ[jt], 0, 0, 0);
                }
            int n = (nt0 + ntl) * 16 + l16;
            float x = sX[n];
            float u = (float)sUh[n];
            float ssum = 0.f;
            #pragma unroll
            for (int jt = 0; jt < 4; ++jt)
                #pragma unroll
                for (int r = 0; r < 4; ++r) {
                    int j = jt * 16 + quad * 4 + r;
                    float kx = (float)kxR[ntl][jt >> 1][(jt & 1) * 4 + r];
                    float dx = x - coordf(j);
                    ssum += kx * tQ[jt][r] + (kx * dx * dx) * tA[jt][r];
                }
            wdd += (double)(u * ssum);
        }
    }
    wdd = blockReduce(wdd, sRed, tid);

    if (tid == 0) {
        double denom = sc * sc + 1e-8;
        ws[s * 3 + 0] = (sc / denom) * t1d - (t1d / denom) * sc;  // ~0
        ws[s * 3 + 1] = wdd;
        ws[s * 3 + 2] = ot;
    }
}

extern "C" __global__ void ot_reduce_kernel(const double* __restrict__ ws,
                                            float* __restrict__ out) {
    int k = threadIdx.x;
    if (k < 3) {
        double acc = 0.0;
        for (int b = 0; b < 32; ++b) acc += ws[b * 3 + k];
        out[k] = (float)acc;
    }
}

extern "C" void kernel_launch(void* const* d_in, const int* in_sizes, int n_in,
                              void* d_out, int out_size, void* d_ws, size_t ws_size,
                              hipStream_t stream) {
    const float* pred   = (const float*)d_in[0];
    const float* normed = (const float*)d_in[1];
    const float* tpts   = (const float*)d_in[2];
    double* ws = (double*)d_ws;

    ot_sinkhorn_mfma<<<dim3(32), dim3(1024), LDS_TOTAL, stream>>>(pred, normed, tpts, ws);
    ot_reduce_kernel<<<dim3(1), dim3(64), 0, stream>>>(ws, (float*)d_out);
}